// Round 16
// baseline (43.291 us; speedup 1.0000x reference)
//
#include <hip/hip_runtime.h>
#include <stdint.h>

// FlagBagEncoder: out[t,:] = mean over {k : flags[t,k] > 0.5} of W[k,:], zeros if empty.
// T=100000, K=512, D=64, fp32 in/out.
//
// v16: v15 (best, 41.52 us) with phase M switched to 32x32x16 over PAIR-TILES.
//   - streams unchanged: each wave row-sequentially reads its own 16 rows
//     (wave pair = one 32-row tile; 6250 active waves as before), exchange to
//     its private sM KB unchanged.
//   - phase M n-split across the pair: wave A -> cols 0-31, wave B -> 32-63.
//     Per wave: 32 MFMA (32x32x16) vs 64 (16x16x32) -> B-LDS reads HALVE
//     (32 ds_read_b128; per-CU 1.56 -> 0.78 MB), MFMA cycles 320 -> 256.
//     af stays LUT-built (v13's doubled-VALU failure mode is gone): per step
//     1 ds_read_u8 (mask byte, from either sM half of the pair) + 2 ds_read_b64
//     (nibble LUT). Two independent acc chains (even/odd steps) for ILP.
//   - numerics: same-kmap-both-operands at 32x32 validated R2; operand swap
//     validated R14; LUT bits identical -> absmax should stay 0.00195.
// Unchanged: 1024-thr blocks (80 KB LDS -> 2 blocks/CU = 32 waves/CU), grid
// 512, stream-first, in-kernel W->sB convert, ONE barrier, LUT in sM[15]
// (waves 14/15 never active: pair group 7 -> slot >= 3584 > 3124).
// k-map (identical for A and B, permutation cancels): k = 16*s + 8*kg + e.

#define T_ROWS 100000
#define K_FLAGS 512
#define D_DIM 64
#define PAIRS (T_ROWS / 32)   // 3125, exact

typedef __attribute__((ext_vector_type(4)))  float f32x4;
typedef __attribute__((ext_vector_type(16))) float f32x16;
typedef __attribute__((ext_vector_type(8)))  short bf16x8;

__device__ __forceinline__ uint32_t f32_to_bf16_rne(float f) {
  union { float f; uint32_t u; } v; v.f = f;
  uint32_t u = v.u;
  return (u + 0x7FFFu + ((u >> 16) & 1u)) >> 16;
}

__global__ __launch_bounds__(1024, 8) void flagbag_kernel(const float* __restrict__ flags,
                                                          const float* __restrict__ W,
                                                          float* __restrict__ out) {
  __shared__ uint4 sB[32 * 2 * 64];     // 64 KB W fragment table: E = s*128 + nt*64 + lane
  __shared__ uint32_t sM[16][256];      // 1 KB per wave mask exchange; sM[15] hosts the LUT

  const int tid  = threadIdx.x;
  const int lane = tid & 63;
  const int wave = tid >> 6;
  const int mate = wave & 1;
  const int pair = (wave >> 1) * 512 + (int)blockIdx.x;   // 8 pair-groups x 512 blocks
  const bool active = (pair < PAIRS);   // waves 14,15 never active (pair >= 3584)
  const int pb = (active ? pair : 0) * 32;
  const int t0 = pb + 16 * mate;        // this wave's 16 stream rows

  // ---- phase L FIRST: row-sequential contiguous read of this wave's 32-KB half ----
  if (active) {
    const float* ft = flags + (size_t)t0 * K_FLAGS + lane * 8;

    uint32_t D0 = 0, D1 = 0, D2 = 0, D3 = 0;   // local rows 0-3 / 4-7 / 8-11 / 12-15
    f32x4 ra[4], rb[4];
#pragma unroll
    for (int r = 0; r < 3; ++r) {
      ra[r] = *reinterpret_cast<const f32x4*>(ft + r * K_FLAGS);
      rb[r] = *reinterpret_cast<const f32x4*>(ft + r * K_FLAGS + 4);
    }
#pragma unroll
    for (int r = 0; r < 16; ++r) {
      if (r + 3 < 16) {   // compile-time under full unroll
        ra[(r + 3) & 3] = *reinterpret_cast<const f32x4*>(ft + (r + 3) * K_FLAGS);
        rb[(r + 3) & 3] = *reinterpret_cast<const f32x4*>(ft + (r + 3) * K_FLAGS + 4);
      }
      const f32x4 a = ra[r & 3], b = rb[r & 3];
      uint32_t byte = 0;
#pragma unroll
      for (int j = 0; j < 4; ++j) {
        byte |= (a[j] > 0.5f) ? (1u << j)       : 0u;
        byte |= (b[j] > 0.5f) ? (1u << (j + 4)) : 0u;
      }
      const uint32_t sh = byte << ((r & 3) * 8);
      if ((r >> 2) == 0) D0 |= sh;
      else if ((r >> 2) == 1) D1 |= sh;
      else if ((r >> 2) == 2) D2 |= sh;
      else D3 |= sh;
    }

    uint32_t* sMw = sM[wave];
    sMw[0 * 64 + (lane ^ 0)]  = D0;
    sMw[1 * 64 + (lane ^ 4)]  = D1;
    sMw[2 * 64 + (lane ^ 8)]  = D2;
    sMw[3 * 64 + (lane ^ 12)] = D3;
  }

  // ---- nibble LUT init: 16 entries x 2 dwords in sM[15] (dead space) ----
  if (tid < 32) {
    const int e = tid >> 1, h = tid & 1;
    const uint32_t d = (((e >> (2 * h)) & 1)     ? 0x00003F80u : 0u) |
                       (((e >> (2 * h + 1)) & 1) ? 0x3F800000u : 0u);
    sM[15][e * 2 + h] = d;
  }

  // ---- W -> bf16 fragment table, 32x32 layout (overlaps other waves' streams) ----
#pragma unroll
  for (int p = 0; p < 4; ++p) {
    const int E  = tid + p * 1024;
    const int s  = E >> 7;          // 0..31
    const int nt = (E >> 6) & 1;
    const int ln = E & 63;
    const int n  = (ln & 31) + 32 * nt;
    const int kb = 16 * s + 8 * (ln >> 5);
    uint32_t r[4];
#pragma unroll
    for (int j = 0; j < 4; ++j) {
      uint32_t lo = f32_to_bf16_rne(W[(size_t)(kb + 2 * j    ) * D_DIM + n]);
      uint32_t hi = f32_to_bf16_rne(W[(size_t)(kb + 2 * j + 1) * D_DIM + n]);
      r[j] = lo | (hi << 16);
    }
    sB[E] = make_uint4(r[0], r[1], r[2], r[3]);
  }
  __syncthreads();   // only barrier: orders sB, both sM halves of each pair, LUT
  if (!active) return;

  // ---- phase M: swapped-operand 32x32x16 MFMA, n-split across the pair ----
  const int trow = lane & 31;       // pair-tile row this lane OWNS (output row pb+trow)
  const int kg   = lane >> 5;       // k-octet group: k = 16s + 8kg + e
  const int lr   = trow & 15;
  const int mj   = lr >> 2, mb = lr & 3, m2 = 2 * mj;
  // mask source: the pair-half holding row trow
  const uint8_t* sMs = reinterpret_cast<const uint8_t*>(sM[(wave & ~1) + (trow >> 4)]);
  const uint32_t* lut = sM[15];

  f32x16 accA, accB;
#pragma unroll
  for (int i = 0; i < 16; ++i) { accA[i] = 0.f; accB[i] = 0.f; }
  int cnt = 0;

  uint4 bc = sB[mate * 64 + lane];   // s = 0
#pragma unroll
  for (int s = 0; s < 32; ++s) {
    uint4 bn;
    if (s + 1 < 32) bn = sB[(s + 1) * 128 + mate * 64 + lane];

    // mask byte: dword mj*64 + 2*(s^m2) + kg, byte mb  (x = 2s+kg, ^4mj == 2(s^2mj)+kg)
    const uint32_t byte = sMs[(size_t)(mj * 64 + 2 * (s ^ m2) + kg) * 4 + mb];
    cnt += __popc(byte);

    // af via nibble LUT: dwords 0,1 <- lo nibble ; 2,3 <- hi nibble
    union { uint32_t d[4]; bf16x8 v; } af;
    const uint2 lo = *reinterpret_cast<const uint2*>(&lut[(byte & 15u) * 2]);
    const uint2 hi = *reinterpret_cast<const uint2*>(&lut[(byte >> 4) * 2]);
    af.d[0] = lo.x; af.d[1] = lo.y; af.d[2] = hi.x; af.d[3] = hi.y;

    // SWAPPED: A = W fragment (my n-half), B = mask fragment. Two chains for ILP.
    if (s & 1)
      accB = __builtin_amdgcn_mfma_f32_32x32x16_bf16(
          *reinterpret_cast<const bf16x8*>(&bc), af.v, accB, 0, 0, 0);
    else
      accA = __builtin_amdgcn_mfma_f32_32x32x16_bf16(
          *reinterpret_cast<const bf16x8*>(&bc), af.v, accA, 0, 0, 0);

    bc = bn;
  }

  // full row count: lanes trow and trow+32 hold the two k-octet halves
  cnt += __shfl_xor(cnt, 32);
  const float inv = (cnt > 0) ? (1.0f / (float)cnt) : 0.0f;

  // ---- epilogue: lane owns output row pb+trow ----
  // C/D: col(lane&31) = mask row; row(reg) = W col = 32*mate + (reg&3) + 8*(reg>>2) + 4*kg
  float* obase = out + (size_t)(pb + trow) * D_DIM + 32 * mate + 4 * kg;
#pragma unroll
  for (int g = 0; g < 4; ++g) {
    f32x4 v;
#pragma unroll
    for (int r = 0; r < 4; ++r) v[r] = (accA[g * 4 + r] + accB[g * 4 + r]) * inv;
    *reinterpret_cast<f32x4*>(obase + 8 * g) = v;   // dwordx4
  }
}

extern "C" void kernel_launch(void* const* d_in, const int* in_sizes, int n_in,
                              void* d_out, int out_size, void* d_ws, size_t ws_size,
                              hipStream_t stream) {
  const float* flags = (const float*)d_in[0];
  const float* W     = (const float*)d_in[1];
  float* out         = (float*)d_out;

  hipLaunchKernelGGL(flagbag_kernel, dim3(512), dim3(1024), 0, stream, flags, W, out);
}

// Round 17
// 41.153 us; speedup vs baseline: 1.0520x; 1.0520x over previous
//
#include <hip/hip_runtime.h>
#include <stdint.h>

// FlagBagEncoder: out[t,:] = mean over {k : flags[t,k] > 0.5} of W[k,:], zeros if empty.
// T=100000, K=512, D=64, fp32 in/out.
//
// v17 == v15 (best, 41.52 us), restored after v16's 32x32 pair-tile regression.
// Design ledger (what's in here and why):
//   - bf16 MFMA with mask exact in bf16; W bf16 rounding -> absmax 0.00195 << 6.3e-3.
//   - phase L FIRST: per-wave row-sequential contiguous 32-KB stream (R10: pattern
//     AND occupancy both required), depth-4 ring, starts at cycle ~0 (R8: +2.7 us).
//   - 1024-thread blocks, 80 KB LDS -> 2 blocks/CU = 32 waves/CU (R7: +6.6 us),
//     grid 512 exact, tile = wave*512 + bid (zero tail rounds).
//   - in-kernel W->sB convert overlapping other waves' streams; ONE barrier.
//   - swapped-operand MFMA (A=W frag, B=mask frag; R14: bit-identical, lane owns
//     output row) -> coalesced dwordx4 epilogue, no shuffles.
//   - af built via 128-B nibble LUT in sM[15] dead space + b128 mask-dword reads
//     (R15: -0.9 us vs VALU af-build).
//   - counts exact via popc of the same mask bytes; k-map identical for A and B
//     (k = 128*kq + 8*s + e) so any within-group permutation cancels.
// Rejected by measurement: B-from-L2 (R9 +8), fused scattered stream (R10 +9),
// pair/32x32 tiles (R11/R13/R16 +4..5), barrier-before-stream (R12 +4).

#define T_ROWS 100000
#define K_FLAGS 512
#define D_DIM 64
#define TILES (T_ROWS / 16)   // 6250, exact

typedef __attribute__((ext_vector_type(4))) float f32x4;
typedef __attribute__((ext_vector_type(8))) short bf16x8;

__device__ __forceinline__ uint32_t f32_to_bf16_rne(float f) {
  union { float f; uint32_t u; } v; v.f = f;
  uint32_t u = v.u;
  return (u + 0x7FFFu + ((u >> 16) & 1u)) >> 16;
}

__global__ __launch_bounds__(1024, 8) void flagbag_kernel(const float* __restrict__ flags,
                                                          const float* __restrict__ W,
                                                          float* __restrict__ out) {
  __shared__ uint4 sB[16 * 4 * 64];     // 64 KB W fragment table: E = s*256 + nt*64 + lane
  __shared__ uint32_t sM[16][256];      // 1 KB per wave mask exchange; sM[15] hosts the LUT

  const int tid  = threadIdx.x;
  const int lane = tid & 63;
  const int wave = tid >> 6;
  const int tile = wave * 512 + (int)blockIdx.x;   // grid = 512 blocks exactly
  const bool active = (tile < TILES);              // waves 13..15: never active
  const int t0 = (active ? tile : 0) * 16;

  // ---- phase L FIRST: row-sequential contiguous read of the 32-KB tile ----
  if (active) {
    const float* ft = flags + (size_t)t0 * K_FLAGS + lane * 8;

    uint32_t D0 = 0, D1 = 0, D2 = 0, D3 = 0;   // rows 0-3 / 4-7 / 8-11 / 12-15
    f32x4 ra[4], rb[4];
#pragma unroll
    for (int r = 0; r < 3; ++r) {
      ra[r] = *reinterpret_cast<const f32x4*>(ft + r * K_FLAGS);
      rb[r] = *reinterpret_cast<const f32x4*>(ft + r * K_FLAGS + 4);
    }
#pragma unroll
    for (int r = 0; r < 16; ++r) {
      if (r + 3 < 16) {   // compile-time under full unroll
        ra[(r + 3) & 3] = *reinterpret_cast<const f32x4*>(ft + (r + 3) * K_FLAGS);
        rb[(r + 3) & 3] = *reinterpret_cast<const f32x4*>(ft + (r + 3) * K_FLAGS + 4);
      }
      const f32x4 a = ra[r & 3], b = rb[r & 3];
      uint32_t byte = 0;
#pragma unroll
      for (int j = 0; j < 4; ++j) {
        byte |= (a[j] > 0.5f) ? (1u << j)       : 0u;
        byte |= (b[j] > 0.5f) ? (1u << (j + 4)) : 0u;
      }
      const uint32_t sh = byte << ((r & 3) * 8);
      if ((r >> 2) == 0) D0 |= sh;
      else if ((r >> 2) == 1) D1 |= sh;
      else if ((r >> 2) == 2) D2 |= sh;
      else D3 |= sh;
    }

    uint32_t* sMw = sM[wave];
    sMw[0 * 64 + (lane ^ 0)]  = D0;
    sMw[1 * 64 + (lane ^ 4)]  = D1;
    sMw[2 * 64 + (lane ^ 8)]  = D2;
    sMw[3 * 64 + (lane ^ 12)] = D3;
  }

  // ---- nibble LUT init: 16 entries x 2 dwords in sM[15] (dead space) ----
  if (tid < 32) {
    const int e = tid >> 1, h = tid & 1;   // entry nibble, dword half (bits 2h, 2h+1)
    const uint32_t d = (((e >> (2 * h)) & 1)     ? 0x00003F80u : 0u) |
                       (((e >> (2 * h + 1)) & 1) ? 0x3F800000u : 0u);
    sM[15][e * 2 + h] = d;
  }

  // ---- W -> bf16 fragment table (overlaps other waves' streams) ----
#pragma unroll
  for (int p = 0; p < 4; ++p) {
    const int E  = tid + p * 1024;
    const int s  = E >> 8;
    const int nt = (E >> 6) & 3;
    const int ln = E & 63;
    const int n  = (ln & 15) + 16 * nt;
    const int kb = 128 * (ln >> 4) + 8 * s;
    uint32_t r[4];
#pragma unroll
    for (int j = 0; j < 4; ++j) {
      uint32_t lo = f32_to_bf16_rne(W[(size_t)(kb + 2 * j    ) * D_DIM + n]);
      uint32_t hi = f32_to_bf16_rne(W[(size_t)(kb + 2 * j + 1) * D_DIM + n]);
      r[j] = lo | (hi << 16);
    }
    sB[E] = make_uint4(r[0], r[1], r[2], r[3]);
  }
  __syncthreads();   // only barrier: orders sB, sM, LUT
  if (!active) return;

  // ---- phase M: swapped-operand MFMA; af from LUT, mask dwords via b128 ----
  const int m  = lane & 15;   // mask row (= output row this lane OWNS)
  const int kq = lane >> 4;
  const int mj = m >> 2, mb = m & 3;
  const uint32_t* sMw = sM[wave];
  const uint32_t* lut = sM[15];

  const uint4* sbl = &sB[lane];
  f32x4 acc[4];
#pragma unroll
  for (int nt = 0; nt < 4; ++nt) acc[nt] = (f32x4){0.f, 0.f, 0.f, 0.f};

  uint4 bc[4], bn[4];
#pragma unroll
  for (int nt = 0; nt < 4; ++nt) bc[nt] = sbl[nt * 64];

  int cnt = 0;
#pragma unroll
  for (int g = 0; g < 4; ++g) {
    // steps 4g..4g+3: their mask dwords are consecutive (x = 16kq + s survives
    // the XOR remap since all offsets are 4-aligned): dword q <-> step 4g+q.
    const uint4 md = *reinterpret_cast<const uint4*>(&sMw[mj * 64 + 16 * kq + 4 * (g ^ mj)]);

#pragma unroll
    for (int q = 0; q < 4; ++q) {
      const int s = 4 * g + q;
      if (s + 1 < 16) {
#pragma unroll
        for (int nt = 0; nt < 4; ++nt) bn[nt] = sbl[((s + 1) * 4 + nt) * 64];
      }
      const uint32_t dw = (q == 0) ? md.x : (q == 1) ? md.y : (q == 2) ? md.z : md.w;
      const uint32_t byte = (dw >> (8 * mb)) & 0xFFu;   // 8 k-bits of row m, k=128kq+8s+e
      cnt += __popc(byte);

      // af via nibble LUT: dwords 0,1 <- lo nibble ; 2,3 <- hi nibble
      union { uint32_t d[4]; bf16x8 v; } af;
      const uint2 lo = *reinterpret_cast<const uint2*>(&lut[(byte & 15u) * 2]);
      const uint2 hi = *reinterpret_cast<const uint2*>(&lut[(byte >> 4) * 2]);
      af.d[0] = lo.x; af.d[1] = lo.y; af.d[2] = hi.x; af.d[3] = hi.y;

      // SWAPPED: A = W fragment, B = mask fragment.
#pragma unroll
      for (int nt = 0; nt < 4; ++nt)
        acc[nt] = __builtin_amdgcn_mfma_f32_16x16x32_bf16(
            *reinterpret_cast<const bf16x8*>(&bc[nt]), af.v, acc[nt], 0, 0, 0);

#pragma unroll
      for (int nt = 0; nt < 4; ++nt) bc[nt] = bn[nt];
    }
  }

  // full row-m count: lanes {m, m+16, m+32, m+48} hold disjoint k-quarters
  cnt += __shfl_xor(cnt, 16);
  cnt += __shfl_xor(cnt, 32);
  const float inv = (cnt > 0) ? (1.0f / (float)cnt) : 0.0f;

  // ---- epilogue: lane owns output row m; 4 coalesced dwordx4 stores ----
  float* obase = out + (size_t)(t0 + m) * D_DIM + 4 * kq;
#pragma unroll
  for (int nt = 0; nt < 4; ++nt) {
    f32x4 v;
#pragma unroll
    for (int r = 0; r < 4; ++r) v[r] = acc[nt][r] * inv;
    *reinterpret_cast<f32x4*>(obase + 16 * nt) = v;   // coalesced dwordx4
  }
}

extern "C" void kernel_launch(void* const* d_in, const int* in_sizes, int n_in,
                              void* d_out, int out_size, void* d_ws, size_t ws_size,
                              hipStream_t stream) {
  const float* flags = (const float*)d_in[0];
  const float* W     = (const float*)d_in[1];
  float* out         = (float*)d_out;

  hipLaunchKernelGGL(flagbag_kernel, dim3(512), dim3(1024), 0, stream, flags, W, out);
}